// Round 3
// baseline (156.223 us; speedup 1.0000x reference)
//
#include <hip/hip_runtime.h>
#include <math.h>

// Quantum dense layer, 12 qubits, DEPTH=1.
// Insight 1: the 66-CNOT cascade composes to the linear GF(2) map
//            dst(s) = s ^ (s>>1)  (binary->Gray), so it is a free index remap.
//            (Derivation: bit j's value when it becomes control is b_j ^ b_{j-1},
//             telescoping across the i<j double loop.)
// Insight 2: one 64-lane wave holds the full 4096-amp complex state in VGPRs
//            (64 complex amps/thread = 128 VGPRs). Wires 0..5 are register-local,
//            wires 6..11 are lane-XOR pairs via __shfl_xor. No LDS in main loop.
// Block = 256 threads = 4 waves = 4 independent rows. Grid = 512 = 2 blocks/CU
// (LDS-limited: 64 KB/block).

#define EPSF 1e-10f

__global__ __launch_bounds__(256, 2) void qdense_kernel(
    const float* __restrict__ x,
    const float* __restrict__ qw,
    float* __restrict__ out)
{
    __shared__ float lds[4][4096];          // 64 KB: one 16 KB slice per wave
    const int wave = threadIdx.x >> 6;
    const int lane = threadIdx.x & 63;
    const int row  = (blockIdx.x << 2) | wave;

    const float* __restrict__ xr = x + (size_t)row * 4096;

    // State: amp index s = (l<<6) | lane, l = 0..63 (register index).
    float ar[64], ai[64];

    // ---- load + squared-norm ----
    float ss = 0.0f;
#pragma unroll
    for (int l = 0; l < 64; ++l) {
        float v = xr[(l << 6) | lane];      // 256B contiguous per instr: coalesced
        ar[l] = v;
        ss = fmaf(v, v, ss);
    }
#pragma unroll
    for (int m = 32; m; m >>= 1) ss += __shfl_xor(ss, m, 64);

    const float nrm = sqrtf(ss);
    if (nrm > EPSF) {
        const float inv = 1.0f / nrm;
#pragma unroll
        for (int l = 0; l < 64; ++l) ar[l] *= inv;
    } else {
#pragma unroll
        for (int l = 0; l < 64; ++l) ar[l] = 0.015625f;   // 1/sqrt(4096)
    }
#pragma unroll
    for (int l = 0; l < 64; ++l) ai[l] = 0.0f;

    // ---- 12 Rot gates ----
    // U = [[p - iq, -r - it], [r - it, p + iq]]
    //   p = cos(th/2)cos((phi+om)/2)   q = cos(th/2)sin((phi+om)/2)
    //   r = sin(th/2)cos((phi-om)/2)   t = sin(th/2)sin((phi-om)/2)
#pragma unroll
    for (int w = 0; w < 12; ++w) {
        const float phi = qw[w * 3 + 0];
        const float th  = qw[w * 3 + 1];
        const float om  = qw[w * 3 + 2];
        const float c = __cosf(0.5f * th), s = __sinf(0.5f * th);
        const float A = 0.5f * (phi + om), B = 0.5f * (phi - om);
        const float p = c * __cosf(A), q = c * __sinf(A);
        const float r = s * __cosf(B), t = s * __sinf(B);

        const int pb = 11 - w;              // bit position of this wire (MSB-first)
        if (pb >= 6) {
            // register-local wire: pair (l0, l0|bit) within the thread
            const int bit = 1 << (pb - 6);
#pragma unroll
            for (int l0 = 0; l0 < 64; ++l0) {
                if (l0 & bit) continue;
                const int l1 = l0 | bit;
                const float a0r = ar[l0], a0i = ai[l0];
                const float a1r = ar[l1], a1i = ai[l1];
                ar[l0] =  p * a0r + q * a0i - r * a1r + t * a1i;
                ai[l0] = -q * a0r + p * a0i - t * a1r - r * a1i;
                ar[l1] =  r * a0r + t * a0i + p * a1r - q * a1i;
                ai[l1] = -t * a0r + r * a0i + q * a1r + p * a1i;
            }
        } else {
            // lane wire: partner = lane ^ (1<<pb); per-thread side select
            const int mask = 1 << pb;
            const int side = (lane >> pb) & 1;
            const float sq = side ? -q : q;
            const float sr = side ? r : -r;
#pragma unroll
            for (int l = 0; l < 64; ++l) {
                const float pr = __shfl_xor(ar[l], mask, 64);
                const float pi = __shfl_xor(ai[l], mask, 64);
                const float mr = ar[l], mi = ai[l];
                ar[l] = p * mr + sq * mi + sr * pr + t * pi;
                ai[l] = p * mi - sq * mr - t * pr + sr * pi;
            }
        }
        // no barrier: waves are fully independent until the LDS epilogue
    }

    // ---- probs, CNOT permutation (Gray map), row sum ----
    float* L = lds[wave];
    float ps = 0.0f;
#pragma unroll
    for (int l = 0; l < 64; ++l) {
        const int s = (l << 6) | lane;
        const float pr2 = fmaf(ar[l], ar[l], ai[l] * ai[l]);
        ps += pr2;
        L[s ^ (s >> 1)] = pr2;              // dst = binary->Gray; 2-way bank alias (free)
    }
#pragma unroll
    for (int m = 32; m; m >>= 1) ps += __shfl_xor(ps, m, 64);

    __syncthreads();                        // drain scattered LDS writes before re-read

    float* __restrict__ orow = out + (size_t)row * 4096;
    if (ps > EPSF) {
        const float scale = 1.0f / ps;      // max(ps,EPS) == ps here
#pragma unroll
        for (int v = 0; v < 16; ++v) {
            const int k = (v << 8) | (lane << 2);
            float4 d = *reinterpret_cast<const float4*>(&L[k]);
            d.x *= scale; d.y *= scale; d.z *= scale; d.w *= scale;
            *reinterpret_cast<float4*>(&orow[k]) = d;
        }
    } else {
        const float u = 1.0f / 4096.0f;
        const float4 d = make_float4(u, u, u, u);
#pragma unroll
        for (int v = 0; v < 16; ++v) {
            const int k = (v << 8) | (lane << 2);
            *reinterpret_cast<float4*>(&orow[k]) = d;
        }
    }
}

extern "C" void kernel_launch(void* const* d_in, const int* in_sizes, int n_in,
                              void* d_out, int out_size, void* d_ws, size_t ws_size,
                              hipStream_t stream) {
    const float* x  = (const float*)d_in[0];   // (2048, 4096) f32
    const float* qw = (const float*)d_in[1];   // (1, 12, 3) f32
    float* out = (float*)d_out;                // (2048, 4096) f32
    qdense_kernel<<<512, 256, 0, stream>>>(x, qw, out);
}

// Round 6
// 109.932 us; speedup vs baseline: 1.4211x; 1.4211x over previous
//
#include <hip/hip_runtime.h>
#include <math.h>

// Quantum dense layer, 12 qubits, DEPTH=1.  v2: 4 waves per row.
// - 66-CNOT cascade == Gray map g = s ^ (s>>1) (validated in v1, absmax 7.6e-6).
// - v1 was latency-bound: 1 wave/row -> only 8 waves/CU (Occupancy 19%, VALU 27%).
// - v2 splits each row over 4 waves: s = [l(4) | w(2) | lane(6)], 16 complex
//   amps/thread (32 VGPRs). Wires 0-3 register-local, 6-11 lane __shfl_xor,
//   4-5 (wave bits) via LDS exchange — legal reorder since distinct-wire
//   1q gates commute. Wave-bit pairs share the same register index, so the
//   exchange is a same-offset read from the partner wave's LDS slice.
// - Block 256 = 1 row, grid 2048 = 8 blocks/CU; LDS 16.4 KB; VGPR cap 64
//   via __launch_bounds__(256,8) -> up to 32 waves/CU.

#define EPSF 1e-10f

__global__ __launch_bounds__(256, 8) void qdense_kernel(
    const float* __restrict__ x,
    const float* __restrict__ qw,
    float* __restrict__ out)
{
    __shared__ float buf[4096];   // 16 KB: SoA exchange (2048 re + 2048 im) / prob staging
    __shared__ float bsum[4];

    const int tid = threadIdx.x;
    const int w   = tid >> 6;     // wave id   = state bits 7:6 (wires 4,5)
    const int ln  = tid & 63;     // lane      = state bits 5:0 (wires 6..11)
    const int row = blockIdx.x;

    const float* __restrict__ xr = x + ((size_t)row << 12);

    float ar[16], ai[16];         // register index l = state bits 11:8 (wires 0..3)

    // ---- load + block squared-norm ----
    float ss = 0.f;
    const int wl = (w << 6) | ln;
#pragma unroll
    for (int l = 0; l < 16; ++l) {
        const float v = xr[(l << 8) | wl];   // per-wave 256B contiguous: coalesced
        ar[l] = v;
        ss = fmaf(v, v, ss);
    }
#pragma unroll
    for (int m = 32; m; m >>= 1) ss += __shfl_xor(ss, m, 64);
    if (ln == 0) bsum[w] = ss;
    __syncthreads();
    const float ss_tot = bsum[0] + bsum[1] + bsum[2] + bsum[3];

    const float nrm = sqrtf(ss_tot);
    if (nrm > EPSF) {
        const float inv = 1.0f / nrm;
#pragma unroll
        for (int l = 0; l < 16; ++l) ar[l] *= inv;
    } else {
#pragma unroll
        for (int l = 0; l < 16; ++l) ar[l] = 0.015625f;   // 1/sqrt(4096)
    }
#pragma unroll
    for (int l = 0; l < 16; ++l) ai[l] = 0.f;

    // ---- register wires (0..3) and lane wires (6..11) ----
    // U = [[p - iq, -r - it], [r - it, p + iq]]  (validated in v1)
#pragma unroll
    for (int wq = 0; wq < 12; ++wq) {
        if (wq == 4 || wq == 5) continue;          // wave wires handled after
        const float phi = qw[wq * 3 + 0];
        const float th  = qw[wq * 3 + 1];
        const float om  = qw[wq * 3 + 2];
        const float c = __cosf(0.5f * th), s = __sinf(0.5f * th);
        const float A = 0.5f * (phi + om), B = 0.5f * (phi - om);
        const float p = c * __cosf(A), q = c * __sinf(A);
        const float r = s * __cosf(B), t = s * __sinf(B);

        const int pb = 11 - wq;                    // state bit of this wire
        if (pb >= 8) {
            // register-local: pair (l0, l0|bit)
            const int bit = 1 << (pb - 8);
#pragma unroll
            for (int l0 = 0; l0 < 16; ++l0) {
                if (l0 & bit) continue;
                const int l1 = l0 | bit;
                const float a0r = ar[l0], a0i = ai[l0];
                const float a1r = ar[l1], a1i = ai[l1];
                ar[l0] =  p * a0r + q * a0i - r * a1r + t * a1i;
                ai[l0] = -q * a0r + p * a0i - t * a1r - r * a1i;
                ar[l1] =  r * a0r + t * a0i + p * a1r - q * a1i;
                ai[l1] = -t * a0r + r * a0i + q * a1r + p * a1i;
            }
        } else {
            // lane wire: partner lane = ln ^ (1<<pb)
            const int mask = 1 << pb;
            const int side = (ln >> pb) & 1;
            const float sq = side ? -q : q;
            const float sr = side ? r : -r;
#pragma unroll
            for (int l = 0; l < 16; ++l) {
                const float pr = __shfl_xor(ar[l], mask, 64);
                const float pi = __shfl_xor(ai[l], mask, 64);
                const float mr = ar[l], mi = ai[l];
                ar[l] = p * mr + sq * mi + sr * pr + t * pi;
                ai[l] = p * mi - sq * mr - t * pr + sr * pi;
            }
        }
    }

    // ---- wave wires (4,5): LDS exchange, 2 chunks of 8 regs, SoA ----
#pragma unroll
    for (int wq = 4; wq <= 5; ++wq) {
        const float phi = qw[wq * 3 + 0];
        const float th  = qw[wq * 3 + 1];
        const float om  = qw[wq * 3 + 2];
        const float c = __cosf(0.5f * th), s = __sinf(0.5f * th);
        const float A = 0.5f * (phi + om), B = 0.5f * (phi - om);
        const float p = c * __cosf(A), q = c * __sinf(A);
        const float r = s * __cosf(B), t = s * __sinf(B);

        const int wmask = (wq == 4) ? 2 : 1;       // wire4 -> w bit1, wire5 -> w bit0
        const int side  = (w & wmask) ? 1 : 0;     // uniform per wave: no divergence
        const float sq = side ? -q : q;
        const float sr = side ? r : -r;
        const int pw = w ^ wmask;
#pragma unroll
        for (int c2 = 0; c2 < 2; ++c2) {
            __syncthreads();                       // buffer free (prior reads done)
#pragma unroll
            for (int rr = 0; rr < 8; ++rr) {
                const int l   = (c2 << 3) | rr;
                const int off = (w << 9) | (rr << 6) | ln;   // stride-1 in ln: conflict-free
                buf[off]        = ar[l];
                buf[2048 + off] = ai[l];
            }
            __syncthreads();
#pragma unroll
            for (int rr = 0; rr < 8; ++rr) {
                const int l   = (c2 << 3) | rr;
                const int off = (pw << 9) | (rr << 6) | ln;
                const float pr = buf[off];
                const float pi = buf[2048 + off];
                const float mr = ar[l], mi = ai[l];
                ar[l] = p * mr + sq * mi + sr * pr + t * pi;
                ai[l] = p * mi - sq * mr - t * pr + sr * pi;
            }
        }
    }

    // ---- probs + block sum + Gray scatter ----
    float p2[16];
    float s2 = 0.f;
#pragma unroll
    for (int l = 0; l < 16; ++l) {
        p2[l] = fmaf(ar[l], ar[l], ai[l] * ai[l]);
        s2 += p2[l];
    }
#pragma unroll
    for (int m = 32; m; m >>= 1) s2 += __shfl_xor(s2, m, 64);

    __syncthreads();                               // protect last exchange reads
    if (ln == 0) bsum[w] = s2;
#pragma unroll
    for (int l = 0; l < 16; ++l) {
        const int sdx = (l << 8) | (w << 6) | ln;
        buf[sdx ^ (sdx >> 1)] = p2[l];             // CNOT cascade = Gray remap; ~2-way bank alias (free)
    }
    __syncthreads();

    const float ps = bsum[0] + bsum[1] + bsum[2] + bsum[3];
    float* __restrict__ orow = out + ((size_t)row << 12);
    if (ps > EPSF) {
        const float sc = 1.0f / ps;
#pragma unroll
        for (int v = 0; v < 4; ++v) {
            const int k = (w << 10) | (v << 8) | (ln << 2);
            float4 d = *reinterpret_cast<const float4*>(&buf[k]);
            d.x *= sc; d.y *= sc; d.z *= sc; d.w *= sc;
            *reinterpret_cast<float4*>(&orow[k]) = d;
        }
    } else {
        const float u = 1.0f / 4096.0f;
        const float4 d = make_float4(u, u, u, u);
#pragma unroll
        for (int v = 0; v < 4; ++v) {
            const int k = (w << 10) | (v << 8) | (ln << 2);
            *reinterpret_cast<float4*>(&orow[k]) = d;
        }
    }
}

extern "C" void kernel_launch(void* const* d_in, const int* in_sizes, int n_in,
                              void* d_out, int out_size, void* d_ws, size_t ws_size,
                              hipStream_t stream) {
    const float* x  = (const float*)d_in[0];   // (2048, 4096) f32
    const float* qw = (const float*)d_in[1];   // (1, 12, 3) f32
    float* out = (float*)d_out;                // (2048, 4096) f32
    qdense_kernel<<<2048, 256, 0, stream>>>(x, qw, out);
}